// Round 1
// 268.000 us; speedup vs baseline: 1.0088x; 1.0088x over previous
//
#include <hip/hip_runtime.h>
#include <hip/hip_bf16.h>
#include <hip/hip_fp16.h>
#include <math.h>

#define NEG_SLOPE 0.2f
#define NCHUNK 1024      // edge chunks (radix partition parallelism)
#define BSHIFT 9         // 512 nodes per coarse bucket
#define BNODES 512

__device__ __forceinline__ float leaky(float x) { return x > 0.f ? x : NEG_SLOPE * x; }

// ---------------- CSR build: deterministic radix partition ----------------
__global__ void chunk_hist(const int* __restrict__ dst, int E, int Ec, int nbuck,
                           int* __restrict__ hmatT) {
    extern __shared__ int hist[];   // nbuck ints
    int c = blockIdx.x;
    for (int b = threadIdx.x; b < nbuck; b += 256) hist[b] = 0;
    __syncthreads();
    int lo = c * Ec, hi = min(E, lo + Ec);
    for (int e = lo + threadIdx.x; e < hi; e += 256) atomicAdd(&hist[dst[e] >> BSHIFT], 1);
    __syncthreads();
    for (int b = threadIdx.x; b < nbuck; b += 256) hmatT[b * NCHUNK + c] = hist[b];
}

__global__ void mat_scan(int* __restrict__ hmatT, int* __restrict__ btot) {
    __shared__ int wsum[4];
    int b = blockIdx.x;
    int t = threadIdx.x;
    int lane = t & 63, wave = t >> 6;
    int base = b * NCHUNK + t * 4;
    int a0 = hmatT[base], a1 = hmatT[base + 1], a2 = hmatT[base + 2], a3 = hmatT[base + 3];
    int ts = a0 + a1 + a2 + a3;
    int incl = ts;
#pragma unroll
    for (int o = 1; o < 64; o <<= 1) {
        int v = __shfl_up(incl, o);
        if (lane >= o) incl += v;
    }
    if (lane == 63) wsum[wave] = incl;
    __syncthreads();
    int wadd = 0;
#pragma unroll
    for (int w = 0; w < 4; w++) if (w < wave) wadd += wsum[w];
    int excl = wadd + incl - ts;
    hmatT[base] = excl;
    hmatT[base + 1] = excl + a0;
    hmatT[base + 2] = excl + a0 + a1;
    hmatT[base + 3] = excl + a0 + a1 + a2;
    if (t == 255) btot[b] = wadd + incl;
}

__global__ void base_scan(const int* __restrict__ btot, int nbuck, int* __restrict__ bbase,
                          int* __restrict__ offs, int N, int E) {
    __shared__ int tsum[256];
    int t = threadIdx.x;
    int v = (t < nbuck) ? btot[t] : 0;
    tsum[t] = v;
    __syncthreads();
    for (int o = 1; o < 256; o <<= 1) {
        int add = (t >= o) ? tsum[t - o] : 0;
        __syncthreads();
        tsum[t] += add;
        __syncthreads();
    }
    if (t <= nbuck) bbase[t] = (t == 0) ? 0 : tsum[t - 1];
    if (t == 0) offs[N] = N + E;
}

__global__ void chunk_scatter(const int* __restrict__ src, const int* __restrict__ dst,
                              int E, int Ec, int nbuck, const int* __restrict__ hmatT,
                              const int* __restrict__ bbase, int* __restrict__ bbuf) {
    extern __shared__ int cur[];   // nbuck ints
    int c = blockIdx.x;
    for (int b = threadIdx.x; b < nbuck; b += 256) cur[b] = bbase[b] + hmatT[b * NCHUNK + c];
    __syncthreads();
    int lo = c * Ec, hi = min(E, lo + Ec);
    for (int e = lo + threadIdx.x; e < hi; e += 256) {
        int d = dst[e];
        int b = d >> BSHIFT;
        int p = atomicAdd(&cur[b], 1);
        bbuf[p] = (src[e] << BSHIFT) | (d & (BNODES - 1));
    }
}

__global__ void bucket_build(const int* __restrict__ bbase, const int* __restrict__ bbuf,
                             int N, int* __restrict__ offs, int* __restrict__ csr) {
    __shared__ int hist[BNODES];
    __shared__ int offl[BNODES];
    __shared__ int cur[BNODES];
    int b = blockIdx.x;
    int t = threadIdx.x;       // 512 threads
    hist[t] = 0;
    __syncthreads();
    int lo = bbase[b], hi = bbase[b + 1];
    for (int j = lo + t; j < hi; j += BNODES) atomicAdd(&hist[bbuf[j] & (BNODES - 1)], 1);
    __syncthreads();
    int own = hist[t];
    for (int o = 1; o < BNODES; o <<= 1) {
        int add = (t >= o) ? hist[t - o] : 0;
        __syncthreads();
        hist[t] += add;
        __syncthreads();
    }
    int excl = hist[t] - own;
    int n = (b << BSHIFT) + t;
    int off_n = n + bbase[b] + excl;
    offl[t] = off_n;
    cur[t] = 0;
    if (n < N) {
        offs[n] = off_n;
        csr[off_n] = n;        // self-loop at slot 0
    }
    __syncthreads();
    for (int j = lo + t; j < hi; j += BNODES) {
        int v = bbuf[j];
        int ld = v & (BNODES - 1);
        int r = atomicAdd(&cur[ld], 1);
        csr[offl[ld] + 1 + r] = v >> BSHIFT;
    }
}

// ---------------- layer 1: h = x@W (h fp16), s = h.a_src, d = h.a_dst ----------------

template <int FIN, int FOUT>
__global__ void transform(const float* __restrict__ xin, const float* __restrict__ W,
                          const float* __restrict__ asrc, const float* __restrict__ adst,
                          __half* __restrict__ h, float* __restrict__ sv, float* __restrict__ dv,
                          int N) {
    constexpr int TPN = FOUT / 4;
    constexpr int BN  = 256 / TPN;
    constexpr int PITCH = FIN + 4;
    __shared__ float xs[BN * PITCH];
    __shared__ float wl[FIN * FOUT];
    __shared__ float al[FOUT], bl[FOUT];
    for (int j = threadIdx.x; j < FIN * FOUT; j += 256) wl[j] = W[j];
    if (threadIdx.x < FOUT) { al[threadIdx.x] = asrc[threadIdx.x]; bl[threadIdx.x] = adst[threadIdx.x]; }
    int base = blockIdx.x * BN;
    constexpr int NV = BN * FIN / 4;
    const float4* xg = (const float4*)xin + (size_t)base * (FIN / 4);
    int limv = ((N - base) * FIN) >> 2;
    for (int v = threadIdx.x; v < NV; v += 256) {
        int n = v / (FIN / 4), c = v % (FIN / 4);
        float4 val = (v < limv) ? xg[v] : make_float4(0.f, 0.f, 0.f, 0.f);
        *(float4*)&xs[n * PITCH + c * 4] = val;
    }
    __syncthreads();
    int node_l = threadIdx.x / TPN;
    int fq = (threadIdx.x % TPN) * 4;
    int node = base + node_l;
    const float* xrow = &xs[node_l * PITCH];
    float4 acc = make_float4(0.f, 0.f, 0.f, 0.f);
#pragma unroll 8
    for (int k = 0; k < FIN; k++) {
        float xv = xrow[k];
        float4 w4 = *(const float4*)&wl[k * FOUT + fq];
        acc.x += xv * w4.x; acc.y += xv * w4.y; acc.z += xv * w4.z; acc.w += xv * w4.w;
    }
    if (node < N) {
        __half2* hp = (__half2*)(h + (size_t)node * FOUT + fq);
        hp[0] = __floats2half2_rn(acc.x, acc.y);
        hp[1] = __floats2half2_rn(acc.z, acc.w);
        float sp = acc.x * al[fq] + acc.y * al[fq + 1] + acc.z * al[fq + 2] + acc.w * al[fq + 3];
        float dp = acc.x * bl[fq] + acc.y * bl[fq + 1] + acc.z * bl[fq + 2] + acc.w * bl[fq + 3];
#pragma unroll
        for (int o = TPN / 2; o > 0; o >>= 1) { sp += __shfl_xor(sp, o); dp += __shfl_xor(dp, o); }
        if (fq == 0) { sv[node] = sp; dv[node] = dp; }
    }
}

// ---------------- fused: GAT aggregate (uint4 lanes, L=FI/8, sv prefetch) + NEXT-LAYER transform ----------------

template <int FI, int FO>
__global__ void gat_trans(const __half* __restrict__ h, const float* __restrict__ sv,
                          const float* __restrict__ dv, const int* __restrict__ offs,
                          const int* __restrict__ csr, const float* __restrict__ bias,
                          const float* __restrict__ Wn, const float* __restrict__ an_s,
                          const float* __restrict__ an_d,
                          __half* __restrict__ h2, float* __restrict__ sv2,
                          float* __restrict__ dv2, int N) {
    constexpr int L = FI / 8;            // lanes per node, 16B (8 halves) each
    constexpr int CPL = FO / L;          // output cols per lane
    constexpr int NPB = 256 / L;
    __shared__ float wl[FI * FO];
    __shared__ float al[FO], bl[FO];
    for (int j = threadIdx.x; j < FI * FO; j += 256) wl[j] = Wn[j];
    if (threadIdx.x < FO) { al[threadIdx.x] = an_s[threadIdx.x]; bl[threadIdx.x] = an_d[threadIdx.x]; }
    __syncthreads();
    int sub = threadIdx.x / L;
    int lane = threadIdx.x % L;
    int wlane = threadIdx.x & 63;
    int sgbase = wlane & ~(L - 1);
    int i = blockIdx.x * NPB + sub;
    if (i >= N) return;
    int beg = offs[i], end = offs[i + 1];
    float di = dv[i];
    float acc[8];
#pragma unroll
    for (int c = 0; c < 8; c++) acc[c] = 0.f;
    float ssum = 0.f;
    int j = beg;
    int n0 = 0, n1 = 0, n2 = 0, n3 = 0;
    float sva = 0.f, svb = 0.f;          // svb only used when L==2
    if (j + 4 <= end) {
        n0 = csr[j]; n1 = csr[j + 1]; n2 = csr[j + 2]; n3 = csr[j + 3];
        if (L >= 4) {
            int k = lane & 3;
            int sel = n0;
            if (k == 1) sel = n1; else if (k == 2) sel = n2; else if (k == 3) sel = n3;
            sva = sv[sel];
        } else {
            sva = sv[lane ? n1 : n0];
            svb = sv[lane ? n3 : n2];
        }
    }
    while (j + 4 <= end) {
        uint4 u0 = *((const uint4*)(h + (size_t)n0 * FI) + lane);
        uint4 u1 = *((const uint4*)(h + (size_t)n1 * FI) + lane);
        uint4 u2 = *((const uint4*)(h + (size_t)n2 * FI) + lane);
        uint4 u3 = *((const uint4*)(h + (size_t)n3 * FI) + lane);
        int jn = j + 4;
        int m0 = 0, m1 = 0, m2 = 0, m3 = 0;
        float nsva = 0.f, nsvb = 0.f;
        if (jn + 4 <= end) {
            m0 = csr[jn]; m1 = csr[jn + 1]; m2 = csr[jn + 2]; m3 = csr[jn + 3];
            if (L >= 4) {
                int k = lane & 3;
                int sel = m0;
                if (k == 1) sel = m1; else if (k == 2) sel = m2; else if (k == 3) sel = m3;
                nsva = sv[sel];
            } else {
                nsva = sv[lane ? m1 : m0];
                nsvb = sv[lane ? m3 : m2];
            }
        }
        float w0, w1, w2, w3;
        if (L >= 4) {
            float myw = __expf(leaky(sva + di));
            w0 = __shfl(myw, sgbase + 0);
            w1 = __shfl(myw, sgbase + 1);
            w2 = __shfl(myw, sgbase + 2);
            w3 = __shfl(myw, sgbase + 3);
        } else {
            float mya = __expf(leaky(sva + di));
            float myb = __expf(leaky(svb + di));
            w0 = __shfl(mya, sgbase + 0);
            w1 = __shfl(mya, sgbase + 1);
            w2 = __shfl(myb, sgbase + 0);
            w3 = __shfl(myb, sgbase + 1);
        }
        ssum += (w0 + w1) + (w2 + w3);
#pragma unroll
        for (int c = 0; c < 4; c++) {
            float2 f0 = __half22float2(((const __half2*)&u0)[c]);
            float2 f1 = __half22float2(((const __half2*)&u1)[c]);
            float2 f2 = __half22float2(((const __half2*)&u2)[c]);
            float2 f3 = __half22float2(((const __half2*)&u3)[c]);
            acc[2 * c]     += w0 * f0.x + w1 * f1.x + w2 * f2.x + w3 * f3.x;
            acc[2 * c + 1] += w0 * f0.y + w1 * f1.y + w2 * f2.y + w3 * f3.y;
        }
        n0 = m0; n1 = m1; n2 = m2; n3 = m3;
        sva = nsva; svb = nsvb;
        j = jn;
    }
    for (; j < end; j++) {
        int srcj = csr[j];
        uint4 u = *((const uint4*)(h + (size_t)srcj * FI) + lane);
        float w = __expf(leaky(sv[srcj] + di));
        ssum += w;
#pragma unroll
        for (int c = 0; c < 4; c++) {
            float2 f = __half22float2(((const __half2*)&u)[c]);
            acc[2 * c]     += w * f.x;
            acc[2 * c + 1] += w * f.y;
        }
    }
    float inv = 1.0f / ssum;
    float4 ba = ((const float4*)bias)[lane * 2];
    float4 bb = ((const float4*)bias)[lane * 2 + 1];
    float yv[8];
    yv[0] = fmaxf(acc[0] * inv + ba.x, 0.f);
    yv[1] = fmaxf(acc[1] * inv + ba.y, 0.f);
    yv[2] = fmaxf(acc[2] * inv + ba.z, 0.f);
    yv[3] = fmaxf(acc[3] * inv + ba.w, 0.f);
    yv[4] = fmaxf(acc[4] * inv + bb.x, 0.f);
    yv[5] = fmaxf(acc[5] * inv + bb.y, 0.f);
    yv[6] = fmaxf(acc[6] * inv + bb.z, 0.f);
    yv[7] = fmaxf(acc[7] * inv + bb.w, 0.f);
    // ---- fused next-layer transform: h2 = y @ Wn, lane owns CPL output cols ----
    int colbase = lane * CPL;
    float oacc[CPL];
#pragma unroll
    for (int c = 0; c < CPL; c++) oacc[c] = 0.f;
#pragma unroll
    for (int jj = 0; jj < L; jj++) {
        float v[8];
#pragma unroll
        for (int r = 0; r < 8; r++) v[r] = __shfl(yv[r], sgbase + jj);
#pragma unroll
        for (int r = 0; r < 8; r++) {
            const float* wrow = &wl[(jj * 8 + r) * FO + colbase];
#pragma unroll
            for (int c = 0; c < CPL; c++) oacc[c] += v[r] * wrow[c];
        }
    }
    __half2 hp[CPL / 2];
#pragma unroll
    for (int c = 0; c < CPL / 2; c++) hp[c] = __floats2half2_rn(oacc[2 * c], oacc[2 * c + 1]);
    *((uint4*)(h2 + (size_t)i * FO + colbase))     = *(uint4*)&hp[0];
    *((uint4*)(h2 + (size_t)i * FO + colbase + 8)) = *(uint4*)&hp[4];
    float sp = 0.f, dp = 0.f;
#pragma unroll
    for (int c = 0; c < CPL; c++) { sp += oacc[c] * al[colbase + c]; dp += oacc[c] * bl[colbase + c]; }
#pragma unroll
    for (int o = 1; o < L; o <<= 1) { sp += __shfl_xor(sp, o); dp += __shfl_xor(dp, o); }
    if (lane == 0) { sv2[i] = sp; dv2[i] = dp; }
}

// ---------------- final layer: single-pass GAT aggregate (uint4 lanes, L=8) ----------------

template <int F>
__global__ void gat_fused(const __half* __restrict__ h, const float* __restrict__ sv,
                          const float* __restrict__ dv, const int* __restrict__ offs,
                          const int* __restrict__ csr, const float* __restrict__ bias,
                          __half* __restrict__ y, int N) {
    constexpr int L = F / 8;             // 8 lanes/node for F=64
    constexpr int NPB = 256 / L;
    int sub = threadIdx.x / L;
    int lane = threadIdx.x % L;
    int wlane = threadIdx.x & 63;
    int sgbase = wlane & ~(L - 1);
    int i = blockIdx.x * NPB + sub;
    if (i >= N) return;
    int beg = offs[i], end = offs[i + 1];
    float di = dv[i];
    float acc[8];
#pragma unroll
    for (int c = 0; c < 8; c++) acc[c] = 0.f;
    float ssum = 0.f;
    int j = beg;
    int n0 = 0, n1 = 0, n2 = 0, n3 = 0;
    float sva = 0.f;
    if (j + 4 <= end) {
        n0 = csr[j]; n1 = csr[j + 1]; n2 = csr[j + 2]; n3 = csr[j + 3];
        int k = lane & 3;
        int sel = n0;
        if (k == 1) sel = n1; else if (k == 2) sel = n2; else if (k == 3) sel = n3;
        sva = sv[sel];
    }
    while (j + 4 <= end) {
        uint4 u0 = *((const uint4*)(h + (size_t)n0 * F) + lane);
        uint4 u1 = *((const uint4*)(h + (size_t)n1 * F) + lane);
        uint4 u2 = *((const uint4*)(h + (size_t)n2 * F) + lane);
        uint4 u3 = *((const uint4*)(h + (size_t)n3 * F) + lane);
        int jn = j + 4;
        int m0 = 0, m1 = 0, m2 = 0, m3 = 0;
        float nsva = 0.f;
        if (jn + 4 <= end) {
            m0 = csr[jn]; m1 = csr[jn + 1]; m2 = csr[jn + 2]; m3 = csr[jn + 3];
            int k = lane & 3;
            int sel = m0;
            if (k == 1) sel = m1; else if (k == 2) sel = m2; else if (k == 3) sel = m3;
            nsva = sv[sel];
        }
        float myw = __expf(leaky(sva + di));
        float w0 = __shfl(myw, sgbase + 0);
        float w1 = __shfl(myw, sgbase + 1);
        float w2 = __shfl(myw, sgbase + 2);
        float w3 = __shfl(myw, sgbase + 3);
        ssum += (w0 + w1) + (w2 + w3);
#pragma unroll
        for (int c = 0; c < 4; c++) {
            float2 f0 = __half22float2(((const __half2*)&u0)[c]);
            float2 f1 = __half22float2(((const __half2*)&u1)[c]);
            float2 f2 = __half22float2(((const __half2*)&u2)[c]);
            float2 f3 = __half22float2(((const __half2*)&u3)[c]);
            acc[2 * c]     += w0 * f0.x + w1 * f1.x + w2 * f2.x + w3 * f3.x;
            acc[2 * c + 1] += w0 * f0.y + w1 * f1.y + w2 * f2.y + w3 * f3.y;
        }
        n0 = m0; n1 = m1; n2 = m2; n3 = m3;
        sva = nsva;
        j = jn;
    }
    for (; j < end; j++) {
        int srcj = csr[j];
        uint4 u = *((const uint4*)(h + (size_t)srcj * F) + lane);
        float w = __expf(leaky(sv[srcj] + di));
        ssum += w;
#pragma unroll
        for (int c = 0; c < 4; c++) {
            float2 f = __half22float2(((const __half2*)&u)[c]);
            acc[2 * c]     += w * f.x;
            acc[2 * c + 1] += w * f.y;
        }
    }
    float inv = 1.0f / ssum;
    float4 ba = ((const float4*)bias)[lane * 2];
    float4 bb = ((const float4*)bias)[lane * 2 + 1];
    __half2 o[4];
    o[0] = __floats2half2_rn(fmaxf(acc[0] * inv + ba.x, 0.f), fmaxf(acc[1] * inv + ba.y, 0.f));
    o[1] = __floats2half2_rn(fmaxf(acc[2] * inv + ba.z, 0.f), fmaxf(acc[3] * inv + ba.w, 0.f));
    o[2] = __floats2half2_rn(fmaxf(acc[4] * inv + bb.x, 0.f), fmaxf(acc[5] * inv + bb.y, 0.f));
    o[3] = __floats2half2_rn(fmaxf(acc[6] * inv + bb.z, 0.f), fmaxf(acc[7] * inv + bb.w, 0.f));
    ((uint4*)(y + (size_t)i * F))[lane] = *(uint4*)&o[0];
}

// ---------------- fused pooling + head (fp16 y in) ----------------

__global__ void pool_head(const __half* __restrict__ y, const float* __restrict__ fcw,
                          const float* __restrict__ fcb, float* __restrict__ out,
                          int N, int G, int C) {
    __shared__ float red[256];
    __shared__ float pl[64];
    int g = blockIdx.x;
    long long gl = g;
    int start = (int)((gl * N + G - 1) / G);
    int end = (int)(((gl + 1) * N + G - 1) / G);
    int f = threadIdx.x & 63, w = threadIdx.x >> 6;
    float m = 0.f;   // post-relu values >= 0
    for (int i = start + w; i < end; i += 4) m = fmaxf(m, __half2float(y[(size_t)i * 64 + f]));
    red[threadIdx.x] = m;
    __syncthreads();
    if (threadIdx.x < 64) {
        pl[f] = fmaxf(fmaxf(red[f], red[64 + f]), fmaxf(red[128 + f], red[192 + f]));
    }
    __syncthreads();
    if (threadIdx.x < 64) {   // wave 0 only
        int c = threadIdx.x;
        float z = -1e30f;
        if (c < C) {
            z = fcb[c];
            for (int k = 0; k < 64; k++) z += pl[k] * fcw[k * 10 + c];
        }
        float zm = z;
#pragma unroll
        for (int o = 1; o < 16; o <<= 1) zm = fmaxf(zm, __shfl_xor(zm, o));
        float e = (c < C) ? __expf(z - zm) : 0.f;
        float se = e;
#pragma unroll
        for (int o = 1; o < 16; o <<= 1) se += __shfl_xor(se, o);
        if (c < C) out[g * C + c] = z - zm - logf(se);
    }
}

// ---------------- launch ----------------

extern "C" void kernel_launch(void* const* d_in, const int* in_sizes, int n_in,
                              void* d_out, int out_size, void* d_ws, size_t ws_size,
                              hipStream_t stream) {
    const float* x    = (const float*)d_in[0];
    const int*   eidx = (const int*)d_in[1];
    const float* W1 = (const float*)d_in[3];
    const float* a1s = (const float*)d_in[4];
    const float* a1d = (const float*)d_in[5];
    const float* b1 = (const float*)d_in[6];
    const float* W2 = (const float*)d_in[7];
    const float* a2s = (const float*)d_in[8];
    const float* a2d = (const float*)d_in[9];
    const float* b2 = (const float*)d_in[10];
    const float* W3 = (const float*)d_in[11];
    const float* a3s = (const float*)d_in[12];
    const float* a3d = (const float*)d_in[13];
    const float* b3 = (const float*)d_in[14];
    const float* fcw = (const float*)d_in[15];
    const float* fcb = (const float*)d_in[16];
    float* out = (float*)d_out;

    const int N = in_sizes[2];
    const int E = in_sizes[1] / 2;
    const int C = in_sizes[16];
    const int G = out_size / C;

    const int* src = eidx;
    const int* dst = eidx + E;

    size_t off = 0;
    auto alloc = [&](size_t bytes) -> void* {
        void* p = (char*)d_ws + off;
        off += (bytes + 255) & ~(size_t)255;
        return p;
    };
    int* offs   = (int*)alloc((size_t)(N + 1) * 4);
    int* csr    = (int*)alloc((size_t)(E + N) * 4);
    float* sbufA = (float*)alloc((size_t)N * 4);
    float* dbufA = (float*)alloc((size_t)N * 4);
    float* sbufB = (float*)alloc((size_t)N * 4);
    float* dbufB = (float*)alloc((size_t)N * 4);
    __half* hA = (__half*)alloc((size_t)N * 64 * 2);   // h1 (16), then h3 (64)
    __half* hB = (__half*)alloc((size_t)N * 64 * 2);   // h2 (32), then y (64)

    const int NBUCK = (N + BNODES - 1) >> BSHIFT;   // 196
    const int Ec = (E + NCHUNK - 1) / NCHUNK;
    int* hmatT = (int*)alloc((size_t)NBUCK * NCHUNK * 4);
    int* btot  = (int*)alloc((size_t)NBUCK * 4);
    int* bbase = (int*)alloc((size_t)(NBUCK + 1) * 4);
    int* bbuf  = (int*)hB;     // alias: hB dead during CSR build (needs 5.2MB <= 12.8MB)

    const size_t histBytes = (size_t)NBUCK * 4;

    // CSR build (5 kernels)
    chunk_hist<<<NCHUNK, 256, histBytes, stream>>>(dst, E, Ec, NBUCK, hmatT);
    mat_scan<<<NBUCK, 256, 0, stream>>>(hmatT, btot);
    base_scan<<<1, 256, 0, stream>>>(btot, NBUCK, bbase, offs, N, E);
    chunk_scatter<<<NCHUNK, 256, histBytes, stream>>>(src, dst, E, Ec, NBUCK, hmatT, bbase, bbuf);
    bucket_build<<<NBUCK, BNODES, 0, stream>>>(bbase, bbuf, N, offs, csr);

    // layer 1 transform: x (fp32) -> h1, sv1, dv1
    transform<128, 16><<<(N + 63) / 64, 256, 0, stream>>>(x, W1, a1s, a1d, hA, sbufA, dbufA, N);
    // layer 1 aggregate + layer 2 transform fused (L=2, 128 nodes/block)
    gat_trans<16, 32><<<(N + 127) / 128, 256, 0, stream>>>(hA, sbufA, dbufA, offs, csr, b1,
                                                           W2, a2s, a2d, hB, sbufB, dbufB, N);
    // layer 2 aggregate + layer 3 transform fused (L=4, 64 nodes/block)
    gat_trans<32, 64><<<(N + 63) / 64, 256, 0, stream>>>(hB, sbufB, dbufB, offs, csr, b2,
                                                         W3, a3s, a3d, hA, sbufA, dbufA, N);
    // layer 3 aggregate: h3 -> y (fp16) (L=8, 32 nodes/block)
    gat_fused<64><<<(N + 31) / 32, 256, 0, stream>>>(hA, sbufA, dbufA, offs, csr, b3, hB, N);

    // pool + head (fused)
    pool_head<<<G, 256, 0, stream>>>(hB, fcw, fcb, out, N, G, C);
}

// Round 2
// 264.203 us; speedup vs baseline: 1.0233x; 1.0144x over previous
//
#include <hip/hip_runtime.h>
#include <hip/hip_bf16.h>
#include <hip/hip_fp16.h>
#include <math.h>

#define NEG_SLOPE 0.2f
#define NCHUNK 1024      // edge chunks (radix partition parallelism)
#define BSHIFT 9         // 512 nodes per coarse bucket
#define BNODES 512

__device__ __forceinline__ float leaky(float x) { return x > 0.f ? x : NEG_SLOPE * x; }
__device__ __forceinline__ int usan(int v, int n) { return ((unsigned)v < (unsigned)n) ? v : 0; }

// ---------------- CSR build: deterministic radix partition ----------------
__global__ void chunk_hist(const int* __restrict__ dst, int E, int Ec, int nbuck,
                           int* __restrict__ hmatT) {
    extern __shared__ int hist[];   // nbuck ints
    int c = blockIdx.x;
    for (int b = threadIdx.x; b < nbuck; b += 256) hist[b] = 0;
    __syncthreads();
    int lo = c * Ec, hi = min(E, lo + Ec);
    for (int e = lo + threadIdx.x; e < hi; e += 256) atomicAdd(&hist[dst[e] >> BSHIFT], 1);
    __syncthreads();
    for (int b = threadIdx.x; b < nbuck; b += 256) hmatT[b * NCHUNK + c] = hist[b];
}

__global__ void mat_scan(int* __restrict__ hmatT, int* __restrict__ btot) {
    __shared__ int wsum[4];
    int b = blockIdx.x;
    int t = threadIdx.x;
    int lane = t & 63, wave = t >> 6;
    int base = b * NCHUNK + t * 4;
    int a0 = hmatT[base], a1 = hmatT[base + 1], a2 = hmatT[base + 2], a3 = hmatT[base + 3];
    int ts = a0 + a1 + a2 + a3;
    int incl = ts;
#pragma unroll
    for (int o = 1; o < 64; o <<= 1) {
        int v = __shfl_up(incl, o);
        if (lane >= o) incl += v;
    }
    if (lane == 63) wsum[wave] = incl;
    __syncthreads();
    int wadd = 0;
#pragma unroll
    for (int w = 0; w < 4; w++) if (w < wave) wadd += wsum[w];
    int excl = wadd + incl - ts;
    hmatT[base] = excl;
    hmatT[base + 1] = excl + a0;
    hmatT[base + 2] = excl + a0 + a1;
    hmatT[base + 3] = excl + a0 + a1 + a2;
    if (t == 255) btot[b] = wadd + incl;
}

__global__ void base_scan(const int* __restrict__ btot, int nbuck, int* __restrict__ bbase,
                          int* __restrict__ offs, int N, int E) {
    __shared__ int tsum[256];
    int t = threadIdx.x;
    int v = (t < nbuck) ? btot[t] : 0;
    tsum[t] = v;
    __syncthreads();
    for (int o = 1; o < 256; o <<= 1) {
        int add = (t >= o) ? tsum[t - o] : 0;
        __syncthreads();
        tsum[t] += add;
        __syncthreads();
    }
    if (t <= nbuck) bbase[t] = (t == 0) ? 0 : tsum[t - 1];
    if (t == 0) offs[N] = N + E;
}

__global__ void chunk_scatter(const int* __restrict__ src, const int* __restrict__ dst,
                              int E, int Ec, int nbuck, const int* __restrict__ hmatT,
                              const int* __restrict__ bbase, int* __restrict__ bbuf) {
    extern __shared__ int cur[];   // nbuck ints
    int c = blockIdx.x;
    for (int b = threadIdx.x; b < nbuck; b += 256) cur[b] = bbase[b] + hmatT[b * NCHUNK + c];
    __syncthreads();
    int lo = c * Ec, hi = min(E, lo + Ec);
    for (int e = lo + threadIdx.x; e < hi; e += 256) {
        int d = dst[e];
        int b = d >> BSHIFT;
        int p = atomicAdd(&cur[b], 1);
        bbuf[p] = (src[e] << BSHIFT) | (d & (BNODES - 1));
    }
}

__global__ void bucket_build(const int* __restrict__ bbase, const int* __restrict__ bbuf,
                             int N, int* __restrict__ offs, int* __restrict__ csr) {
    __shared__ int hist[BNODES];
    __shared__ int offl[BNODES];
    __shared__ int cur[BNODES];
    int b = blockIdx.x;
    int t = threadIdx.x;       // 512 threads
    hist[t] = 0;
    __syncthreads();
    int lo = bbase[b], hi = bbase[b + 1];
    for (int j = lo + t; j < hi; j += BNODES) atomicAdd(&hist[bbuf[j] & (BNODES - 1)], 1);
    __syncthreads();
    int own = hist[t];
    for (int o = 1; o < BNODES; o <<= 1) {
        int add = (t >= o) ? hist[t - o] : 0;
        __syncthreads();
        hist[t] += add;
        __syncthreads();
    }
    int excl = hist[t] - own;
    int n = (b << BSHIFT) + t;
    int off_n = n + bbase[b] + excl;
    offl[t] = off_n;
    cur[t] = 0;
    if (n < N) {
        offs[n] = off_n;
        csr[off_n] = n;        // self-loop at slot 0
    }
    __syncthreads();
    for (int j = lo + t; j < hi; j += BNODES) {
        int v = bbuf[j];
        int ld = v & (BNODES - 1);
        int r = atomicAdd(&cur[ld], 1);
        csr[offl[ld] + 1 + r] = v >> BSHIFT;
    }
}

// ---------------- layer 1: h = x@W (h fp16), s = h.a_src, d = h.a_dst ----------------

template <int FIN, int FOUT>
__global__ void transform(const float* __restrict__ xin, const float* __restrict__ W,
                          const float* __restrict__ asrc, const float* __restrict__ adst,
                          __half* __restrict__ h, float* __restrict__ sv, float* __restrict__ dv,
                          int N) {
    constexpr int TPN = FOUT / 4;
    constexpr int BN  = 256 / TPN;
    constexpr int PITCH = FIN + 4;
    __shared__ float xs[BN * PITCH];
    __shared__ float wl[FIN * FOUT];
    __shared__ float al[FOUT], bl[FOUT];
    for (int j = threadIdx.x; j < FIN * FOUT; j += 256) wl[j] = W[j];
    if (threadIdx.x < FOUT) { al[threadIdx.x] = asrc[threadIdx.x]; bl[threadIdx.x] = adst[threadIdx.x]; }
    int base = blockIdx.x * BN;
    constexpr int NV = BN * FIN / 4;
    const float4* xg = (const float4*)xin + (size_t)base * (FIN / 4);
    int limv = ((N - base) * FIN) >> 2;
    for (int v = threadIdx.x; v < NV; v += 256) {
        int n = v / (FIN / 4), c = v % (FIN / 4);
        float4 val = (v < limv) ? xg[v] : make_float4(0.f, 0.f, 0.f, 0.f);
        *(float4*)&xs[n * PITCH + c * 4] = val;
    }
    __syncthreads();
    int node_l = threadIdx.x / TPN;
    int fq = (threadIdx.x % TPN) * 4;
    int node = base + node_l;
    const float* xrow = &xs[node_l * PITCH];
    float4 acc = make_float4(0.f, 0.f, 0.f, 0.f);
#pragma unroll 8
    for (int k = 0; k < FIN; k++) {
        float xv = xrow[k];
        float4 w4 = *(const float4*)&wl[k * FOUT + fq];
        acc.x += xv * w4.x; acc.y += xv * w4.y; acc.z += xv * w4.z; acc.w += xv * w4.w;
    }
    if (node < N) {
        __half2* hp = (__half2*)(h + (size_t)node * FOUT + fq);
        hp[0] = __floats2half2_rn(acc.x, acc.y);
        hp[1] = __floats2half2_rn(acc.z, acc.w);
        float sp = acc.x * al[fq] + acc.y * al[fq + 1] + acc.z * al[fq + 2] + acc.w * al[fq + 3];
        float dp = acc.x * bl[fq] + acc.y * bl[fq + 1] + acc.z * bl[fq + 2] + acc.w * bl[fq + 3];
#pragma unroll
        for (int o = TPN / 2; o > 0; o >>= 1) { sp += __shfl_xor(sp, o); dp += __shfl_xor(dp, o); }
        if (fq == 0) { sv[node] = sp; dv[node] = dp; }
    }
}

// ---------------- fused GAT aggregate: split-2 half-subs + depth-1 pipeline + next-layer transform --------

template <int FI, int FO>
__global__ void gat_trans(const __half* __restrict__ h, const float* __restrict__ sv,
                          const float* __restrict__ dv, const int* __restrict__ offs,
                          const int* __restrict__ csr, const float* __restrict__ bias,
                          const float* __restrict__ Wn, const float* __restrict__ an_s,
                          const float* __restrict__ an_d,
                          __half* __restrict__ h2, float* __restrict__ sv2,
                          float* __restrict__ dv2, int N) {
    constexpr int L  = FI / 8;           // lanes per half-sub (16B of h each)
    constexpr int L2 = 2 * L;            // lanes per node (two halves split the edge list)
    constexpr int CPL = FO / L2;         // output cols per lane in epilogue (== 8 here)
    constexpr int NPB = 256 / L2;        // nodes per block
    __shared__ float wl[FI * FO];
    __shared__ float al[FO], bl[FO];
    for (int j = threadIdx.x; j < FI * FO; j += 256) wl[j] = Wn[j];
    if (threadIdx.x < FO) { al[threadIdx.x] = an_s[threadIdx.x]; bl[threadIdx.x] = an_d[threadIdx.x]; }
    __syncthreads();
    int lane  = threadIdx.x % L;         // within half-sub
    int lane2 = threadIdx.x % L2;        // within node group
    int half  = (threadIdx.x / L) & 1;
    int wlane = threadIdx.x & 63;
    int sgbase  = wlane & ~(L - 1);      // half-sub base (weight shuffles)
    int grpbase = wlane & ~(L2 - 1);     // node-group base (epilogue shuffles)
    int i = blockIdx.x * NPB + threadIdx.x / L2;
    if (i >= N) return;
    int beg = offs[i], end = offs[i + 1];
    float di = dv[i];
    float acc[8];
#pragma unroll
    for (int c = 0; c < 8; c++) acc[c] = 0.f;
    float ssum = 0.f;
    const int k3 = lane & 3;

    // ---- depth-1 pipelined batch loop; this half's batches start at beg+4*half, stride 8
    int j0 = beg + 4 * half;
    int j1 = j0 + 8;
    bool vA = (j0 + 4 <= end);
    bool vB = (j1 + 4 <= end);
    int j0e = vA ? j0 : beg;
    int a0 = usan(csr[j0e], N),     a1 = usan(csr[j0e + 1], N);
    int a2 = usan(csr[j0e + 2], N), a3 = usan(csr[j0e + 3], N);
    uint4 uA0 = *((const uint4*)(h + (size_t)a0 * FI) + lane);
    uint4 uA1 = *((const uint4*)(h + (size_t)a1 * FI) + lane);
    uint4 uA2 = *((const uint4*)(h + (size_t)a2 * FI) + lane);
    uint4 uA3 = *((const uint4*)(h + (size_t)a3 * FI) + lane);
    float svA, svA2 = 0.f;
    if constexpr (L >= 4) {
        int sel = a0;
        if (k3 == 1) sel = a1; else if (k3 == 2) sel = a2; else if (k3 == 3) sel = a3;
        svA = sv[sel];
    } else {
        svA  = sv[lane ? a1 : a0];
        svA2 = sv[lane ? a3 : a2];
    }
    int j1e = vB ? j1 : beg;
    int b0 = usan(csr[j1e], N),     b1 = usan(csr[j1e + 1], N);
    int b2 = usan(csr[j1e + 2], N), b3 = usan(csr[j1e + 3], N);
    while (vA) {
        int j2 = j1 + 8;
        bool vC = vB && (j2 + 4 <= end);
        // prefetch next batch's h rows + sv using B indices; csr for batch after
        uint4 uB0 = *((const uint4*)(h + (size_t)b0 * FI) + lane);
        uint4 uB1 = *((const uint4*)(h + (size_t)b1 * FI) + lane);
        uint4 uB2 = *((const uint4*)(h + (size_t)b2 * FI) + lane);
        uint4 uB3 = *((const uint4*)(h + (size_t)b3 * FI) + lane);
        float svB, svB2 = 0.f;
        if constexpr (L >= 4) {
            int sel = b0;
            if (k3 == 1) sel = b1; else if (k3 == 2) sel = b2; else if (k3 == 3) sel = b3;
            svB = sv[sel];
        } else {
            svB  = sv[lane ? b1 : b0];
            svB2 = sv[lane ? b3 : b2];
        }
        int j2e = vC ? j2 : beg;
        int c0 = usan(csr[j2e], N),     c1 = usan(csr[j2e + 1], N);
        int c2 = usan(csr[j2e + 2], N), c3 = usan(csr[j2e + 3], N);
        // ---- compute batch A (loads issued one iteration ago)
        float w0, w1, w2, w3;
        if constexpr (L >= 4) {
            float myw = __expf(leaky(svA + di));
            w0 = __shfl(myw, sgbase + 0);
            w1 = __shfl(myw, sgbase + 1);
            w2 = __shfl(myw, sgbase + 2);
            w3 = __shfl(myw, sgbase + 3);
        } else {
            float mya = __expf(leaky(svA + di));
            float myb = __expf(leaky(svA2 + di));
            w0 = __shfl(mya, sgbase + 0);
            w1 = __shfl(mya, sgbase + 1);
            w2 = __shfl(myb, sgbase + 0);
            w3 = __shfl(myb, sgbase + 1);
        }
        ssum += (w0 + w1) + (w2 + w3);
#pragma unroll
        for (int c = 0; c < 4; c++) {
            float2 f0 = __half22float2(((const __half2*)&uA0)[c]);
            float2 f1 = __half22float2(((const __half2*)&uA1)[c]);
            float2 f2 = __half22float2(((const __half2*)&uA2)[c]);
            float2 f3 = __half22float2(((const __half2*)&uA3)[c]);
            acc[2 * c]     += w0 * f0.x + w1 * f1.x + w2 * f2.x + w3 * f3.x;
            acc[2 * c + 1] += w0 * f0.y + w1 * f1.y + w2 * f2.y + w3 * f3.y;
        }
        // rotate pipeline state
        uA0 = uB0; uA1 = uB1; uA2 = uB2; uA3 = uB3;
        svA = svB; svA2 = svB2;
        b0 = c0; b1 = c1; b2 = c2; b3 = c3;
        j0 = j1; j1 = j2; vA = vB; vB = vC;
    }
    // ---- flat tail (this half owns it iff 0 < end - j0 < 4); clamped offsets keep lines shared
    int rem = end - j0;
    if (rem > 0) {
        int o1 = rem > 1 ? 1 : 0;
        int o2 = rem > 2 ? 2 : o1;
        int t0 = usan(csr[j0], N), t1 = usan(csr[j0 + o1], N), t2 = usan(csr[j0 + o2], N);
        uint4 r0 = *((const uint4*)(h + (size_t)t0 * FI) + lane);
        uint4 r1 = *((const uint4*)(h + (size_t)t1 * FI) + lane);
        uint4 r2 = *((const uint4*)(h + (size_t)t2 * FI) + lane);
        float s0 = sv[t0], s1 = sv[t1], s2 = sv[t2];
        float w0t = __expf(leaky(s0 + di));
        float w1t = rem > 1 ? __expf(leaky(s1 + di)) : 0.f;
        float w2t = rem > 2 ? __expf(leaky(s2 + di)) : 0.f;
        ssum += w0t + w1t + w2t;
#pragma unroll
        for (int c = 0; c < 4; c++) {
            float2 f0 = __half22float2(((const __half2*)&r0)[c]);
            float2 f1 = __half22float2(((const __half2*)&r1)[c]);
            float2 f2 = __half22float2(((const __half2*)&r2)[c]);
            acc[2 * c]     += w0t * f0.x + w1t * f1.x + w2t * f2.x;
            acc[2 * c + 1] += w0t * f0.y + w1t * f1.y + w2t * f2.y;
        }
    }
    // ---- combine the two halves (both end up with the full sums)
#pragma unroll
    for (int c = 0; c < 8; c++) acc[c] += __shfl_xor(acc[c], L);
    ssum += __shfl_xor(ssum, L);

    float inv = 1.0f / ssum;
    float4 ba = ((const float4*)bias)[lane * 2];
    float4 bb = ((const float4*)bias)[lane * 2 + 1];
    float yv[8];
    yv[0] = fmaxf(acc[0] * inv + ba.x, 0.f);
    yv[1] = fmaxf(acc[1] * inv + ba.y, 0.f);
    yv[2] = fmaxf(acc[2] * inv + ba.z, 0.f);
    yv[3] = fmaxf(acc[3] * inv + ba.w, 0.f);
    yv[4] = fmaxf(acc[4] * inv + bb.x, 0.f);
    yv[5] = fmaxf(acc[5] * inv + bb.y, 0.f);
    yv[6] = fmaxf(acc[6] * inv + bb.z, 0.f);
    yv[7] = fmaxf(acc[7] * inv + bb.w, 0.f);
    // ---- fused next-layer transform over the full L2-lane group: h2 = y @ Wn
    int colbase = lane2 * CPL;           // CPL == 8
    float oacc[CPL];
#pragma unroll
    for (int c = 0; c < CPL; c++) oacc[c] = 0.f;
#pragma unroll
    for (int jj = 0; jj < L; jj++) {     // feature slice jj lives on lane grpbase+jj
        float v[8];
#pragma unroll
        for (int r = 0; r < 8; r++) v[r] = __shfl(yv[r], grpbase + jj);
#pragma unroll
        for (int r = 0; r < 8; r++) {
            const float* wrow = &wl[(jj * 8 + r) * FO + colbase];
#pragma unroll
            for (int c = 0; c < CPL; c++) oacc[c] += v[r] * wrow[c];
        }
    }
    __half2 hp[CPL / 2];
#pragma unroll
    for (int c = 0; c < CPL / 2; c++) hp[c] = __floats2half2_rn(oacc[2 * c], oacc[2 * c + 1]);
    *((uint4*)(h2 + (size_t)i * FO + colbase)) = *(uint4*)&hp[0];
    float sp = 0.f, dp = 0.f;
#pragma unroll
    for (int c = 0; c < CPL; c++) { sp += oacc[c] * al[colbase + c]; dp += oacc[c] * bl[colbase + c]; }
#pragma unroll
    for (int o = 1; o < L2; o <<= 1) { sp += __shfl_xor(sp, o); dp += __shfl_xor(dp, o); }
    if (lane2 == 0) { sv2[i] = sp; dv2[i] = dp; }
}

// ---------------- final layer: split-2 + pipelined GAT aggregate ----------------

template <int F>
__global__ void gat_fused(const __half* __restrict__ h, const float* __restrict__ sv,
                          const float* __restrict__ dv, const int* __restrict__ offs,
                          const int* __restrict__ csr, const float* __restrict__ bias,
                          __half* __restrict__ y, int N) {
    constexpr int L  = F / 8;            // 8 lanes per half-sub for F=64
    constexpr int L2 = 2 * L;
    constexpr int NPB = 256 / L2;
    int lane  = threadIdx.x % L;
    int half  = (threadIdx.x / L) & 1;
    int wlane = threadIdx.x & 63;
    int sgbase = wlane & ~(L - 1);
    int i = blockIdx.x * NPB + threadIdx.x / L2;
    if (i >= N) return;
    int beg = offs[i], end = offs[i + 1];
    float di = dv[i];
    float acc[8];
#pragma unroll
    for (int c = 0; c < 8; c++) acc[c] = 0.f;
    float ssum = 0.f;
    const int k3 = lane & 3;

    int j0 = beg + 4 * half;
    int j1 = j0 + 8;
    bool vA = (j0 + 4 <= end);
    bool vB = (j1 + 4 <= end);
    int j0e = vA ? j0 : beg;
    int a0 = usan(csr[j0e], N),     a1 = usan(csr[j0e + 1], N);
    int a2 = usan(csr[j0e + 2], N), a3 = usan(csr[j0e + 3], N);
    uint4 uA0 = *((const uint4*)(h + (size_t)a0 * F) + lane);
    uint4 uA1 = *((const uint4*)(h + (size_t)a1 * F) + lane);
    uint4 uA2 = *((const uint4*)(h + (size_t)a2 * F) + lane);
    uint4 uA3 = *((const uint4*)(h + (size_t)a3 * F) + lane);
    int sel = a0;
    if (k3 == 1) sel = a1; else if (k3 == 2) sel = a2; else if (k3 == 3) sel = a3;
    float svA = sv[sel];
    int j1e = vB ? j1 : beg;
    int b0 = usan(csr[j1e], N),     b1 = usan(csr[j1e + 1], N);
    int b2 = usan(csr[j1e + 2], N), b3 = usan(csr[j1e + 3], N);
    while (vA) {
        int j2 = j1 + 8;
        bool vC = vB && (j2 + 4 <= end);
        uint4 uB0 = *((const uint4*)(h + (size_t)b0 * F) + lane);
        uint4 uB1 = *((const uint4*)(h + (size_t)b1 * F) + lane);
        uint4 uB2 = *((const uint4*)(h + (size_t)b2 * F) + lane);
        uint4 uB3 = *((const uint4*)(h + (size_t)b3 * F) + lane);
        int selB = b0;
        if (k3 == 1) selB = b1; else if (k3 == 2) selB = b2; else if (k3 == 3) selB = b3;
        float svB = sv[selB];
        int j2e = vC ? j2 : beg;
        int c0 = usan(csr[j2e], N),     c1 = usan(csr[j2e + 1], N);
        int c2 = usan(csr[j2e + 2], N), c3 = usan(csr[j2e + 3], N);
        // compute batch A
        float myw = __expf(leaky(svA + di));
        float w0 = __shfl(myw, sgbase + 0);
        float w1 = __shfl(myw, sgbase + 1);
        float w2 = __shfl(myw, sgbase + 2);
        float w3 = __shfl(myw, sgbase + 3);
        ssum += (w0 + w1) + (w2 + w3);
#pragma unroll
        for (int c = 0; c < 4; c++) {
            float2 f0 = __half22float2(((const __half2*)&uA0)[c]);
            float2 f1 = __half22float2(((const __half2*)&uA1)[c]);
            float2 f2 = __half22float2(((const __half2*)&uA2)[c]);
            float2 f3 = __half22float2(((const __half2*)&uA3)[c]);
            acc[2 * c]     += w0 * f0.x + w1 * f1.x + w2 * f2.x + w3 * f3.x;
            acc[2 * c + 1] += w0 * f0.y + w1 * f1.y + w2 * f2.y + w3 * f3.y;
        }
        uA0 = uB0; uA1 = uB1; uA2 = uB2; uA3 = uB3;
        svA = svB;
        b0 = c0; b1 = c1; b2 = c2; b3 = c3;
        j0 = j1; j1 = j2; vA = vB; vB = vC;
    }
    int rem = end - j0;
    if (rem > 0) {
        int o1 = rem > 1 ? 1 : 0;
        int o2 = rem > 2 ? 2 : o1;
        int t0 = usan(csr[j0], N), t1 = usan(csr[j0 + o1], N), t2 = usan(csr[j0 + o2], N);
        uint4 r0 = *((const uint4*)(h + (size_t)t0 * F) + lane);
        uint4 r1 = *((const uint4*)(h + (size_t)t1 * F) + lane);
        uint4 r2 = *((const uint4*)(h + (size_t)t2 * F) + lane);
        float s0 = sv[t0], s1 = sv[t1], s2 = sv[t2];
        float w0t = __expf(leaky(s0 + di));
        float w1t = rem > 1 ? __expf(leaky(s1 + di)) : 0.f;
        float w2t = rem > 2 ? __expf(leaky(s2 + di)) : 0.f;
        ssum += w0t + w1t + w2t;
#pragma unroll
        for (int c = 0; c < 4; c++) {
            float2 f0 = __half22float2(((const __half2*)&r0)[c]);
            float2 f1 = __half22float2(((const __half2*)&r1)[c]);
            float2 f2 = __half22float2(((const __half2*)&r2)[c]);
            acc[2 * c]     += w0t * f0.x + w1t * f1.x + w2t * f2.x;
            acc[2 * c + 1] += w0t * f0.y + w1t * f1.y + w2t * f2.y;
        }
    }
    // combine halves
#pragma unroll
    for (int c = 0; c < 8; c++) acc[c] += __shfl_xor(acc[c], L);
    ssum += __shfl_xor(ssum, L);
    if (half == 0) {
        float inv = 1.0f / ssum;
        float4 ba = ((const float4*)bias)[lane * 2];
        float4 bb = ((const float4*)bias)[lane * 2 + 1];
        __half2 o[4];
        o[0] = __floats2half2_rn(fmaxf(acc[0] * inv + ba.x, 0.f), fmaxf(acc[1] * inv + ba.y, 0.f));
        o[1] = __floats2half2_rn(fmaxf(acc[2] * inv + ba.z, 0.f), fmaxf(acc[3] * inv + ba.w, 0.f));
        o[2] = __floats2half2_rn(fmaxf(acc[4] * inv + bb.x, 0.f), fmaxf(acc[5] * inv + bb.y, 0.f));
        o[3] = __floats2half2_rn(fmaxf(acc[6] * inv + bb.z, 0.f), fmaxf(acc[7] * inv + bb.w, 0.f));
        ((uint4*)(y + (size_t)i * F))[lane] = *(uint4*)&o[0];
    }
}

// ---------------- fused pooling + head (fp16 y in) ----------------

__global__ void pool_head(const __half* __restrict__ y, const float* __restrict__ fcw,
                          const float* __restrict__ fcb, float* __restrict__ out,
                          int N, int G, int C) {
    __shared__ float red[256];
    __shared__ float pl[64];
    int g = blockIdx.x;
    long long gl = g;
    int start = (int)((gl * N + G - 1) / G);
    int end = (int)(((gl + 1) * N + G - 1) / G);
    int f = threadIdx.x & 63, w = threadIdx.x >> 6;
    float m = 0.f;   // post-relu values >= 0
    for (int i = start + w; i < end; i += 4) m = fmaxf(m, __half2float(y[(size_t)i * 64 + f]));
    red[threadIdx.x] = m;
    __syncthreads();
    if (threadIdx.x < 64) {
        pl[f] = fmaxf(fmaxf(red[f], red[64 + f]), fmaxf(red[128 + f], red[192 + f]));
    }
    __syncthreads();
    if (threadIdx.x < 64) {   // wave 0 only
        int c = threadIdx.x;
        float z = -1e30f;
        if (c < C) {
            z = fcb[c];
            for (int k = 0; k < 64; k++) z += pl[k] * fcw[k * 10 + c];
        }
        float zm = z;
#pragma unroll
        for (int o = 1; o < 16; o <<= 1) zm = fmaxf(zm, __shfl_xor(zm, o));
        float e = (c < C) ? __expf(z - zm) : 0.f;
        float se = e;
#pragma unroll
        for (int o = 1; o < 16; o <<= 1) se += __shfl_xor(se, o);
        if (c < C) out[g * C + c] = z - zm - logf(se);
    }
}

// ---------------- launch ----------------

extern "C" void kernel_launch(void* const* d_in, const int* in_sizes, int n_in,
                              void* d_out, int out_size, void* d_ws, size_t ws_size,
                              hipStream_t stream) {
    const float* x    = (const float*)d_in[0];
    const int*   eidx = (const int*)d_in[1];
    const float* W1 = (const float*)d_in[3];
    const float* a1s = (const float*)d_in[4];
    const float* a1d = (const float*)d_in[5];
    const float* b1 = (const float*)d_in[6];
    const float* W2 = (const float*)d_in[7];
    const float* a2s = (const float*)d_in[8];
    const float* a2d = (const float*)d_in[9];
    const float* b2 = (const float*)d_in[10];
    const float* W3 = (const float*)d_in[11];
    const float* a3s = (const float*)d_in[12];
    const float* a3d = (const float*)d_in[13];
    const float* b3 = (const float*)d_in[14];
    const float* fcw = (const float*)d_in[15];
    const float* fcb = (const float*)d_in[16];
    float* out = (float*)d_out;

    const int N = in_sizes[2];
    const int E = in_sizes[1] / 2;
    const int C = in_sizes[16];
    const int G = out_size / C;

    const int* src = eidx;
    const int* dst = eidx + E;

    size_t off = 0;
    auto alloc = [&](size_t bytes) -> void* {
        void* p = (char*)d_ws + off;
        off += (bytes + 255) & ~(size_t)255;
        return p;
    };
    int* offs   = (int*)alloc((size_t)(N + 1) * 4);
    int* csr    = (int*)alloc((size_t)(E + N) * 4 + 256);   // slack for clamped prologue reads
    float* sbufA = (float*)alloc((size_t)N * 4);
    float* dbufA = (float*)alloc((size_t)N * 4);
    float* sbufB = (float*)alloc((size_t)N * 4);
    float* dbufB = (float*)alloc((size_t)N * 4);
    __half* hA = (__half*)alloc((size_t)N * 64 * 2);   // h1 (16), then h3 (64)
    __half* hB = (__half*)alloc((size_t)N * 64 * 2);   // h2 (32), then y (64)

    const int NBUCK = (N + BNODES - 1) >> BSHIFT;   // 196
    const int Ec = (E + NCHUNK - 1) / NCHUNK;
    int* hmatT = (int*)alloc((size_t)NBUCK * NCHUNK * 4);
    int* btot  = (int*)alloc((size_t)NBUCK * 4);
    int* bbase = (int*)alloc((size_t)(NBUCK + 1) * 4);
    int* bbuf  = (int*)hB;     // alias: hB dead during CSR build (needs 5.2MB <= 12.8MB)

    const size_t histBytes = (size_t)NBUCK * 4;

    // CSR build (5 kernels)
    chunk_hist<<<NCHUNK, 256, histBytes, stream>>>(dst, E, Ec, NBUCK, hmatT);
    mat_scan<<<NBUCK, 256, 0, stream>>>(hmatT, btot);
    base_scan<<<1, 256, 0, stream>>>(btot, NBUCK, bbase, offs, N, E);
    chunk_scatter<<<NCHUNK, 256, histBytes, stream>>>(src, dst, E, Ec, NBUCK, hmatT, bbase, bbuf);
    bucket_build<<<NBUCK, BNODES, 0, stream>>>(bbase, bbuf, N, offs, csr);

    // layer 1 transform: x (fp32) -> h1, sv1, dv1
    transform<128, 16><<<(N + 63) / 64, 256, 0, stream>>>(x, W1, a1s, a1d, hA, sbufA, dbufA, N);
    // layer 1 aggregate + layer 2 transform fused (L=2 halves, 64 nodes/block)
    gat_trans<16, 32><<<(N + 63) / 64, 256, 0, stream>>>(hA, sbufA, dbufA, offs, csr, b1,
                                                         W2, a2s, a2d, hB, sbufB, dbufB, N);
    // layer 2 aggregate + layer 3 transform fused (L=4 halves, 32 nodes/block)
    gat_trans<32, 64><<<(N + 31) / 32, 256, 0, stream>>>(hB, sbufB, dbufB, offs, csr, b2,
                                                         W3, a3s, a3d, hA, sbufA, dbufA, N);
    // layer 3 aggregate: h3 -> y (fp16) (L=8 halves, 16 nodes/block)
    gat_fused<64><<<(N + 15) / 16, 256, 0, stream>>>(hA, sbufA, dbufA, offs, csr, b3, hB, N);

    // pool + head (fused)
    pool_head<<<G, 256, 0, stream>>>(hB, fcw, fcb, out, N, G, C);
}